// Round 10
// baseline (279.409 us; speedup 1.0000x reference)
//
#include <hip/hip_runtime.h>

#define N_NODES 50000
#define N_EDGES 800000
#define CAP 48
#define PB_BLOCKS 2560
typedef _Float16 f16;
// IN_F = 64, OUT_F = 64, EDGE_F = 16, d_in1 = 144
// NOTE: harness passes ALL integer inputs as int32 — edge_index is int32[2*E],
// src = ei[e], dst = ei[E+e].
// NOTE (round 3): hipLaunchCooperativeKernel broke the harness. NEVER coop.
// NOTE (round 6): few hot global atomic counters = serialization disaster.
// NOTE (rounds 5-8): prebuild's ~110us was vmcnt-serialized wave-uniform x
// loads (wc[64] starves landing regs); fixed via LDS-row broadcast (269->234).
// NOTE (round 9): __shfl == ds_bpermute HONORS EXEC — reading from an
// INACTIVE source lane is undefined. Lane-predicated staging around __shfl
// corrupted deg>32 nodes non-deterministically (absmax 0.94/468). Stage must
// be ALL-LANES-ACTIVE with a clamped index (dup writes benign). readlane is
// immune (ignores exec).
// Round 10: clamped depth-32 stage; xa fp16 (halves the scattered gather
// stream); xb stays fp32 (its quant error is coherent x deg — keep exact).

#define FMA16(acc, ep, wreg)                                                 \
    {                                                                        \
        float4 _e0 = (ep)[0], _e1 = (ep)[1], _e2 = (ep)[2], _e3 = (ep)[3];   \
        acc += _e0.x * wreg[0];  acc += _e0.y * wreg[1];                     \
        acc += _e0.z * wreg[2];  acc += _e0.w * wreg[3];                     \
        acc += _e1.x * wreg[4];  acc += _e1.y * wreg[5];                     \
        acc += _e1.z * wreg[6];  acc += _e1.w * wreg[7];                     \
        acc += _e2.x * wreg[8];  acc += _e2.y * wreg[9];                     \
        acc += _e2.z * wreg[10]; acc += _e2.w * wreg[11];                    \
        acc += _e3.x * wreg[12]; acc += _e3.y * wreg[13];                    \
        acc += _e3.z * wreg[14]; acc += _e3.w * wreg[15];                    \
    }

// ---------------------------------------------------------------------------
// prebuild_kernel: EVERY block does
//   (1) build chunk: grid-stride over edges, bucket e by dst
//   (2) pre chunk: xa = x @ W1[0:64,:] (fp16), xb = x @ W1[64:128,:] (fp32)
//       per-lane coalesced x load -> per-wave LDS row -> broadcast
//       ds_read_b128; next row software-pipelined; 4 accumulator chains.
// cnt/ocnt must be zeroed before launch (memsetAsync).
// ---------------------------------------------------------------------------
__global__ __launch_bounds__(256) void prebuild_kernel(
    const float* __restrict__ x, const float* __restrict__ W1,
    f16* __restrict__ xa, float* __restrict__ xb,
    const int* __restrict__ ei, unsigned* __restrict__ cnt,
    unsigned* __restrict__ ocnt, unsigned* __restrict__ slot,
    unsigned* __restrict__ oflow)
{
    __shared__ __align__(16) float srow[4][64];   // per-wave x-row buffer

    const int tid = threadIdx.x;
    const int bid = blockIdx.x;

    // ---- build part: bucket edges by dst (store edge id only, 4 B) ----
    for (int e = bid * 256 + tid; e < N_EDGES; e += PB_BLOCKS * 256) {
        const int d = ei[N_EDGES + e];
        const unsigned pos = atomicAdd(&cnt[d], 1u);
        if (pos < CAP) {
            slot[(size_t)d * CAP + pos] = (unsigned)e;
        } else {
            const unsigned oi = atomicAdd(ocnt, 1u);
            oflow[oi] = (unsigned)e;
        }
    }

    // ---- pre part: wave per (node-subset, product) ----
    const int w = tid >> 6;
    const int j = tid & 63;
    const int gw = bid * 4 + w;
    const int p = gw & 1;              // 0 -> xa (f16), 1 -> xb (f32)
    const int pair = gw >> 1;
    const int npair = PB_BLOCKS * 2;   // 5120

    float wc[64];
#pragma unroll
    for (int k = 0; k < 64; ++k) wc[k] = W1[(p * 64 + k) * 64 + j];

    if (pair < N_NODES) {
        float xv = x[(size_t)pair * 64 + j];          // pipelined row element
        for (int i = pair; i < N_NODES; i += npair) {
            srow[w][j] = xv;                           // wave-internal LDS write
            const int inext = i + npair;
            float xnext = 0.f;
            if (inext < N_NODES) xnext = x[(size_t)inext * 64 + j];

            float a0 = 0.f, a1 = 0.f, a2 = 0.f, a3 = 0.f;
#pragma unroll
            for (int k4 = 0; k4 < 4; ++k4) {
                const float4 v0 = *(const float4*)&srow[w][k4 * 16 + 0];
                const float4 v1 = *(const float4*)&srow[w][k4 * 16 + 4];
                const float4 v2 = *(const float4*)&srow[w][k4 * 16 + 8];
                const float4 v3 = *(const float4*)&srow[w][k4 * 16 + 12];
                a0 += v0.x * wc[k4 * 16 + 0];  a0 += v0.y * wc[k4 * 16 + 1];
                a0 += v0.z * wc[k4 * 16 + 2];  a0 += v0.w * wc[k4 * 16 + 3];
                a1 += v1.x * wc[k4 * 16 + 4];  a1 += v1.y * wc[k4 * 16 + 5];
                a1 += v1.z * wc[k4 * 16 + 6];  a1 += v1.w * wc[k4 * 16 + 7];
                a2 += v2.x * wc[k4 * 16 + 8];  a2 += v2.y * wc[k4 * 16 + 9];
                a2 += v2.z * wc[k4 * 16 + 10]; a2 += v2.w * wc[k4 * 16 + 11];
                a3 += v3.x * wc[k4 * 16 + 12]; a3 += v3.y * wc[k4 * 16 + 13];
                a3 += v3.z * wc[k4 * 16 + 14]; a3 += v3.w * wc[k4 * 16 + 15];
            }
            const float val = (a0 + a1) + (a2 + a3);
            if (p) xb[(size_t)i * 64 + j] = val;          // wave-uniform branch
            else   xa[(size_t)i * 64 + j] = (f16)val;
            xv = xnext;
        }
    }
}

// ---------------------------------------------------------------------------
// nodefused_kernel: one wave per dst node.
//   hacc = sum_e relu(xa[src]+xb[n]+ea@W1c+b1)    (aggregation)
//   out[n] = hacc @ W2 + dcap*b2                  (W2 hoisted out of seg-sum)
// Chunk depth 32 (whole node in one chunk for deg<=32); stage is
// ALL-LANES-ACTIVE with clamped index (see round-9 note). xa fp16, xb fp32.
// ---------------------------------------------------------------------------
__global__ __launch_bounds__(256) void nodefused_kernel(
    const f16* __restrict__ xa, const float* __restrict__ xb,
    const float* __restrict__ ea, const unsigned* __restrict__ slot,
    const int* __restrict__ ei, const unsigned* __restrict__ cnt,
    const float* __restrict__ W1, const float* __restrict__ b1,
    const float* __restrict__ W2, const float* __restrict__ b2,
    float* __restrict__ out)
{
    __shared__ __align__(16) float sea[4][CAP * 16];   // 12 KB / block

    const int w = threadIdx.x >> 6;
    const int j = threadIdx.x & 63;
    const int n = blockIdx.x * 4 + w;

    float w1c[16];
#pragma unroll
    for (int k = 0; k < 16; ++k) w1c[k] = W1[(128 + k) * 64 + j];
    const float b1j = b1[j];
    const float b2j = b2[j];

    const int deg = (int)cnt[n];
    const int dcap = deg < CAP ? deg : CAP;

    int ev = 0, sv = 0;
    if (j < dcap) {
        ev = (int)slot[(size_t)n * CAP + j];
        sv = ei[ev];
    }

    const float base = xb[(size_t)n * 64 + j] + b1j;

    float hacc = 0.f;
    if (dcap > 0) {
        const int sub = j >> 1;        // edge of chunk this lane stages (0..31)
        const int hh  = j & 1;         // which 8-float half of that edge

        for (int b0 = 0; b0 < dcap; b0 += 32) {
            // ---- stage ea rows of edges b0..b0+31 (2 x b128 per lane) ----
            // ALL lanes active; clamped index -> __shfl source lane always
            // active (round-9 lesson); duplicate writes carry identical data.
            {
                const int ii = b0 + sub;
                const int ic = ii < dcap ? ii : dcap - 1;
                const unsigned eid = (unsigned)__shfl(ev, ic);
                const float4* er =
                    (const float4*)(ea + (size_t)eid * 16 + hh * 8);
                float4 v0 = er[0], v1 = er[1];
                float4* dp = (float4*)&sea[w][ic * 16 + hh * 8];
                dp[0] = v0; dp[1] = v1;
            }
            // ---- issue 32 xa gathers into registers (static indexing) ----
            float xv[32];
#pragma unroll
            for (int t = 0; t < 32; ++t) {
                const int ii = b0 + t;
                if (ii < dcap) {                     // wave-uniform guard
                    const unsigned ss =
                        (unsigned)__builtin_amdgcn_readlane(sv, ii);
                    xv[t] = (float)xa[(size_t)ss * 64 + j];
                } else {
                    xv[t] = 0.f;
                }
            }
            // ---- consume up to 32 edges ----
#pragma unroll
            for (int t = 0; t < 32; ++t) {
                const int ii = b0 + t;
                if (ii < dcap) {                     // wave-uniform guard
                    const float4* ep = (const float4*)&sea[w][ii * 16];
                    float acc = base + xv[t];
                    FMA16(acc, ep, w1c);
                    hacc += fmaxf(acc, 0.f);
                }
            }
        }
    }

    // ---- fused epilogue: out[n] = hacc @ W2 + dcap * b2 ----
    sea[w][j] = hacc;                  // broadcast via LDS (wave-internal)
    float msg = (float)dcap * b2j;
#pragma unroll
    for (int k4 = 0; k4 < 16; ++k4) {
        float4 hv = *(const float4*)&sea[w][k4 * 4];     // uniform broadcast
        msg += hv.x * W2[(k4 * 4 + 0) * 64 + j];
        msg += hv.y * W2[(k4 * 4 + 1) * 64 + j];
        msg += hv.z * W2[(k4 * 4 + 2) * 64 + j];
        msg += hv.w * W2[(k4 * 4 + 3) * 64 + j];
    }
    out[(size_t)n * 64 + j] = msg;
}

// ---------------------------------------------------------------------------
// overflow_kernel: correctness net (expected 0 edges). Runs AFTER nodefused.
// ---------------------------------------------------------------------------
__global__ __launch_bounds__(256) void overflow_kernel(
    const f16* __restrict__ xa, const float* __restrict__ xb,
    const int* __restrict__ ei, const float* __restrict__ ea,
    const float* __restrict__ W1, const float* __restrict__ b1,
    const float* __restrict__ W2, const float* __restrict__ b2,
    const unsigned* __restrict__ ocnt, const unsigned* __restrict__ oflow,
    float* __restrict__ out)
{
    const unsigned oc = *ocnt;
    if (oc == 0) return;
    const int w = threadIdx.x >> 6;
    const int j = threadIdx.x & 63;
    unsigned idx = blockIdx.x * 4 + w;
    const unsigned stride = gridDim.x * 4;
    for (; idx < oc; idx += stride) {
        const int e = (int)oflow[idx];
        const int s = ei[e];
        const int dd = ei[N_EDGES + e];
        float acc = (float)xa[(size_t)s * 64 + j] +
                    xb[(size_t)dd * 64 + j] + b1[j];
        for (int k = 0; k < 16; ++k)
            acc += ea[(size_t)e * 16 + k] * W1[(128 + k) * 64 + j];
        const float h = fmaxf(acc, 0.f);
        float msg = b2[j];
        for (int k = 0; k < 64; ++k) msg += __shfl(h, k) * W2[k * 64 + j];
        unsafeAtomicAdd(&out[(size_t)dd * 64 + j], msg);
    }
}

// ---------------------------------------------------------------------------
// OLD PATH kernels (ws too small for bucketed pipeline) — fp32 throughout
// ---------------------------------------------------------------------------
__global__ __launch_bounds__(256) void pre_kernel(
    const float* __restrict__ x, const float* __restrict__ W1,
    float* __restrict__ xa, float* __restrict__ xb)
{
    const int w = threadIdx.x >> 6;
    const int j = threadIdx.x & 63;
    const int gw = blockIdx.x * 4 + w;
    const int p = gw & 1;
    const int pair = gw >> 1;
    const int npair = (gridDim.x * 4) >> 1;

    float wc[64];
#pragma unroll
    for (int k = 0; k < 64; ++k) wc[k] = W1[(p * 64 + k) * 64 + j];
    float* __restrict__ outp = p ? xb : xa;
    for (int i = pair; i < N_NODES; i += npair) {
        const float4* xr = (const float4*)&x[(size_t)i * 64];
        float acc = 0.f;
#pragma unroll
        for (int k4 = 0; k4 < 16; ++k4) {
            float4 xv = xr[k4];
            acc += xv.x * wc[k4 * 4 + 0];
            acc += xv.y * wc[k4 * 4 + 1];
            acc += xv.z * wc[k4 * 4 + 2];
            acc += xv.w * wc[k4 * 4 + 3];
        }
        outp[(size_t)i * 64 + j] = acc;
    }
}

__global__ __launch_bounds__(256) void edge_kernel(
    const float* __restrict__ xa, const float* __restrict__ xb,
    const int* __restrict__ ei,
    const float* __restrict__ edge_attr,
    const float* __restrict__ W1, const float* __restrict__ b1,
    const float* __restrict__ W2, const float* __restrict__ b2,
    float* __restrict__ out)
{
    __shared__ __align__(16) float eas[4][256];
    __shared__ __align__(16) float hs[4][16][64];

    const int w = threadIdx.x >> 6;
    const int j = threadIdx.x & 63;
    const int wt = blockIdx.x * 4 + w;
    const long eb = (long)wt * 16;

    float w1c[16];
    float w2c[64];
#pragma unroll
    for (int k = 0; k < 16; ++k) w1c[k] = W1[(128 + k) * 64 + j];
#pragma unroll
    for (int k = 0; k < 64; ++k) w2c[k] = W2[k * 64 + j];
    const float b1j = b1[j];
    const float b2j = b2[j];

    int idxv = 0;
    if (j < 16)       idxv = ei[eb + j];
    else if (j < 32)  idxv = ei[(long)N_EDGES + eb + (j - 16)];

    {
        float4 ev = *(const float4*)&edge_attr[eb * 16 + j * 4];
        *(float4*)&eas[w][j * 4] = ev;
    }

#pragma unroll 4
    for (int e = 0; e < 16; ++e) {
        const int s  = __shfl(idxv, e);
        const int dd = __shfl(idxv, 16 + e);

        float acc = xa[(long)s * 64 + j] + xb[(long)dd * 64 + j] + b1j;
#pragma unroll
        for (int k4 = 0; k4 < 4; ++k4) {
            float4 ev = *(const float4*)&eas[w][e * 16 + k4 * 4];
            acc += ev.x * w1c[k4 * 4 + 0];
            acc += ev.y * w1c[k4 * 4 + 1];
            acc += ev.z * w1c[k4 * 4 + 2];
            acc += ev.w * w1c[k4 * 4 + 3];
        }
        const float h = fmaxf(acc, 0.f);
        hs[w][e][j] = h;

        float msg = b2j;
#pragma unroll
        for (int k4 = 0; k4 < 16; ++k4) {
            float4 hv = *(const float4*)&hs[w][e][k4 * 4];
            msg += hv.x * w2c[k4 * 4 + 0];
            msg += hv.y * w2c[k4 * 4 + 1];
            msg += hv.z * w2c[k4 * 4 + 2];
            msg += hv.w * w2c[k4 * 4 + 3];
        }
        unsafeAtomicAdd(&out[(long)dd * 64 + j], msg);
    }
}

__global__ __launch_bounds__(256) void fallback_kernel(
    const float* __restrict__ x, const int* __restrict__ ei,
    const float* __restrict__ edge_attr,
    const float* __restrict__ W1, const float* __restrict__ b1,
    const float* __restrict__ W2, const float* __restrict__ b2,
    float* __restrict__ out)
{
    const int w = threadIdx.x >> 6;
    const int j = threadIdx.x & 63;
    const long e = (long)blockIdx.x * 4 + w;
    if (e >= N_EDGES) return;
    const int s  = ei[e];
    const int dd = ei[(long)N_EDGES + e];

    float acc = b1[j];
    for (int k = 0; k < 64; ++k) acc += x[(long)s  * 64 + k] * W1[k * 64 + j];
    for (int k = 0; k < 64; ++k) acc += x[(long)dd * 64 + k] * W1[(64 + k) * 64 + j];
    for (int k = 0; k < 16; ++k) acc += edge_attr[e * 16 + k] * W1[(128 + k) * 64 + j];
    const float h = fmaxf(acc, 0.f);

    float msg = b2[j];
    for (int k = 0; k < 64; ++k) msg += __shfl(h, k) * W2[k * 64 + j];
    unsafeAtomicAdd(&out[(long)dd * 64 + j], msg);
}

extern "C" void kernel_launch(void* const* d_in, const int* in_sizes, int n_in,
                              void* d_out, int out_size, void* d_ws, size_t ws_size,
                              hipStream_t stream) {
    const float* x   = (const float*)d_in[0];
    const int*   ei  = (const int*)d_in[1];
    const float* ea  = (const float*)d_in[2];
    const float* W1  = (const float*)d_in[3];
    const float* b1  = (const float*)d_in[4];
    const float* W2  = (const float*)d_in[5];
    const float* b2  = (const float*)d_in[6];
    float* out = (float*)d_out;

    const size_t NF = (size_t)N_NODES * 64;
    const size_t need_main = NF * 2 + NF * 4               // xa (f16), xb (f32)
                           + (size_t)N_NODES * 4 + 256     // cnt, ocnt(+pad)
                           + (size_t)N_NODES * CAP * 4     // slot (edge id)
                           + (size_t)N_EDGES * 4;          // oflow
    const size_t need_old = 2 * NF * 4;

    if (ws_size >= need_main) {
        char* p = (char*)d_ws;
        f16*      xauf  = (f16*)p;      p += NF * 2;
        float*    xbuf  = (float*)p;    p += NF * 4;
        unsigned* cnt   = (unsigned*)p; p += (size_t)N_NODES * 4;
        unsigned* ocnt  = (unsigned*)p; p += 256;
        unsigned* slot  = (unsigned*)p; p += (size_t)N_NODES * CAP * 4;
        unsigned* oflow = (unsigned*)p;

        hipMemsetAsync(cnt, 0, (size_t)N_NODES * 4 + 256, stream);
        prebuild_kernel<<<PB_BLOCKS, 256, 0, stream>>>(
            x, W1, xauf, xbuf, ei, cnt, ocnt, slot, oflow);
        nodefused_kernel<<<N_NODES / 4, 256, 0, stream>>>(
            xauf, xbuf, ea, slot, ei, cnt, W1, b1, W2, b2, out);
        overflow_kernel<<<16, 256, 0, stream>>>(xauf, xbuf, ei, ea, W1, b1,
                                                W2, b2, ocnt, oflow, out);
    } else if (ws_size >= need_old) {
        hipMemsetAsync(out, 0, (size_t)N_NODES * 64 * sizeof(float), stream);
        float* xauf = (float*)d_ws;
        float* xbuf = xauf + NF;
        pre_kernel<<<512, 256, 0, stream>>>(x, W1, xauf, xbuf);
        edge_kernel<<<N_EDGES / 64, 256, 0, stream>>>(xauf, xbuf, ei, ea,
                                                      W1, b1, W2, b2, out);
    } else {
        hipMemsetAsync(out, 0, (size_t)N_NODES * 64 * sizeof(float), stream);
        fallback_kernel<<<N_EDGES / 4, 256, 0, stream>>>(x, ei, ea,
                                                         W1, b1, W2, b2, out);
    }
}

// Round 11
// 229.950 us; speedup vs baseline: 1.2151x; 1.2151x over previous
//
#include <hip/hip_runtime.h>

#define N_NODES 50000
#define N_EDGES 800000
#define CAP 48
#define PB_BLOCKS 2560
typedef _Float16 f16;
// IN_F = 64, OUT_F = 64, EDGE_F = 16, d_in1 = 144
// NOTE: harness passes ALL integer inputs as int32 — edge_index is int32[2*E],
// src = ei[e], dst = ei[E+e].
// NOTE (round 3): hipLaunchCooperativeKernel broke the harness. NEVER coop.
// NOTE (round 6): few hot global atomic counters = serialization disaster.
// NOTE (rounds 5-8): prebuild's ~110us was vmcnt-serialized wave-uniform x
// loads (wc[64] starves landing regs); fixed via LDS-row broadcast (269->234).
// NOTE (round 9): __shfl == ds_bpermute HONORS EXEC — inactive source lane is
// undefined. Stage must be ALL-LANES-ACTIVE with clamped index. readlane is
// immune (ignores exec).
// NOTE (round 10): depth-32 stage (byte 32*j pattern) = 16-way LDS bank
// conflicts (387K) + xv[32] exceeded VGPR budget -> compiler serialized the
// gathers (VALUBusy 70->42%, dur 86->135us). Round 8's 16-deep contiguous
// stage (byte 16*j) is the proven geometry. fp16 xa itself was fine
// (FETCH 183->135MB, absmax unchanged 0.0625).
// Round 11: round-8 nodefused structure verbatim + fp16 xa only.

#define FMA16(acc, ep, wreg)                                                 \
    {                                                                        \
        float4 _e0 = (ep)[0], _e1 = (ep)[1], _e2 = (ep)[2], _e3 = (ep)[3];   \
        acc += _e0.x * wreg[0];  acc += _e0.y * wreg[1];                     \
        acc += _e0.z * wreg[2];  acc += _e0.w * wreg[3];                     \
        acc += _e1.x * wreg[4];  acc += _e1.y * wreg[5];                     \
        acc += _e1.z * wreg[6];  acc += _e1.w * wreg[7];                     \
        acc += _e2.x * wreg[8];  acc += _e2.y * wreg[9];                     \
        acc += _e2.z * wreg[10]; acc += _e2.w * wreg[11];                    \
        acc += _e3.x * wreg[12]; acc += _e3.y * wreg[13];                    \
        acc += _e3.z * wreg[14]; acc += _e3.w * wreg[15];                    \
    }

// ---------------------------------------------------------------------------
// prebuild_kernel: EVERY block does
//   (1) build chunk: grid-stride over edges, bucket e by dst
//   (2) pre chunk: xa = x @ W1[0:64,:] (fp16), xb = x @ W1[64:128,:] (fp32)
//       per-lane coalesced x load -> per-wave LDS row -> broadcast
//       ds_read_b128; next row software-pipelined; 4 accumulator chains.
// cnt/ocnt must be zeroed before launch (memsetAsync).
// ---------------------------------------------------------------------------
__global__ __launch_bounds__(256) void prebuild_kernel(
    const float* __restrict__ x, const float* __restrict__ W1,
    f16* __restrict__ xa, float* __restrict__ xb,
    const int* __restrict__ ei, unsigned* __restrict__ cnt,
    unsigned* __restrict__ ocnt, unsigned* __restrict__ slot,
    unsigned* __restrict__ oflow)
{
    __shared__ __align__(16) float srow[4][64];   // per-wave x-row buffer

    const int tid = threadIdx.x;
    const int bid = blockIdx.x;

    // ---- build part: bucket edges by dst (store edge id only, 4 B) ----
    for (int e = bid * 256 + tid; e < N_EDGES; e += PB_BLOCKS * 256) {
        const int d = ei[N_EDGES + e];
        const unsigned pos = atomicAdd(&cnt[d], 1u);
        if (pos < CAP) {
            slot[(size_t)d * CAP + pos] = (unsigned)e;
        } else {
            const unsigned oi = atomicAdd(ocnt, 1u);
            oflow[oi] = (unsigned)e;
        }
    }

    // ---- pre part: wave per (node-subset, product) ----
    const int w = tid >> 6;
    const int j = tid & 63;
    const int gw = bid * 4 + w;
    const int p = gw & 1;              // 0 -> xa (f16), 1 -> xb (f32)
    const int pair = gw >> 1;
    const int npair = PB_BLOCKS * 2;   // 5120

    float wc[64];
#pragma unroll
    for (int k = 0; k < 64; ++k) wc[k] = W1[(p * 64 + k) * 64 + j];

    if (pair < N_NODES) {
        float xv = x[(size_t)pair * 64 + j];          // pipelined row element
        for (int i = pair; i < N_NODES; i += npair) {
            srow[w][j] = xv;                           // wave-internal LDS write
            const int inext = i + npair;
            float xnext = 0.f;
            if (inext < N_NODES) xnext = x[(size_t)inext * 64 + j];

            float a0 = 0.f, a1 = 0.f, a2 = 0.f, a3 = 0.f;
#pragma unroll
            for (int k4 = 0; k4 < 4; ++k4) {
                const float4 v0 = *(const float4*)&srow[w][k4 * 16 + 0];
                const float4 v1 = *(const float4*)&srow[w][k4 * 16 + 4];
                const float4 v2 = *(const float4*)&srow[w][k4 * 16 + 8];
                const float4 v3 = *(const float4*)&srow[w][k4 * 16 + 12];
                a0 += v0.x * wc[k4 * 16 + 0];  a0 += v0.y * wc[k4 * 16 + 1];
                a0 += v0.z * wc[k4 * 16 + 2];  a0 += v0.w * wc[k4 * 16 + 3];
                a1 += v1.x * wc[k4 * 16 + 4];  a1 += v1.y * wc[k4 * 16 + 5];
                a1 += v1.z * wc[k4 * 16 + 6];  a1 += v1.w * wc[k4 * 16 + 7];
                a2 += v2.x * wc[k4 * 16 + 8];  a2 += v2.y * wc[k4 * 16 + 9];
                a2 += v2.z * wc[k4 * 16 + 10]; a2 += v2.w * wc[k4 * 16 + 11];
                a3 += v3.x * wc[k4 * 16 + 12]; a3 += v3.y * wc[k4 * 16 + 13];
                a3 += v3.z * wc[k4 * 16 + 14]; a3 += v3.w * wc[k4 * 16 + 15];
            }
            const float val = (a0 + a1) + (a2 + a3);
            if (p) xb[(size_t)i * 64 + j] = val;          // wave-uniform branch
            else   xa[(size_t)i * 64 + j] = (f16)val;
            xv = xnext;
        }
    }
}

// ---------------------------------------------------------------------------
// nodefused_kernel: one wave per dst node.  (round-8 structure, fp16 xa)
//   hacc = sum_e relu(xa[src]+xb[n]+ea@W1c+b1)    (aggregation)
//   out[n] = hacc @ W2 + dcap*b2                  (W2 hoisted out of seg-sum)
// Chunked depth-16: per 16-edge chunk, stage 16 ea rows with one b128/lane
// at contiguous byte 16*j (conflict-free, measured 0 in r8), issue 16 xa
// gathers into registers, consume via uniform broadcast ds_read + FMA16.
// ---------------------------------------------------------------------------
__global__ __launch_bounds__(256) void nodefused_kernel(
    const f16* __restrict__ xa, const float* __restrict__ xb,
    const float* __restrict__ ea, const unsigned* __restrict__ slot,
    const int* __restrict__ ei, const unsigned* __restrict__ cnt,
    const float* __restrict__ W1, const float* __restrict__ b1,
    const float* __restrict__ W2, const float* __restrict__ b2,
    float* __restrict__ out)
{
    __shared__ __align__(16) float sea[4][CAP * 16];   // 12 KB / block

    const int w = threadIdx.x >> 6;
    const int j = threadIdx.x & 63;
    const int n = blockIdx.x * 4 + w;

    float w1c[16];
#pragma unroll
    for (int k = 0; k < 16; ++k) w1c[k] = W1[(128 + k) * 64 + j];
    const float b1j = b1[j];
    const float b2j = b2[j];

    const int deg = (int)cnt[n];
    const int dcap = deg < CAP ? deg : CAP;

    int ev = 0, sv = 0;
    if (j < dcap) {
        ev = (int)slot[(size_t)n * CAP + j];
        sv = ei[ev];
    }

    const float base = xb[(size_t)n * 64 + j] + b1j;

    float hacc = 0.f;
    if (dcap > 0) {
        const int sub = j >> 2;        // which edge of the chunk this lane stages
        const int q   = j & 3;         // which float4 quarter of that edge

        for (int b0 = 0; b0 < dcap; b0 += 16) {
            // ---- stage ea rows of edges b0..b0+15 into LDS (1 b128/lane) ----
            // ALL lanes active, clamped index (r9 lesson); lane j writes LDS
            // byte 16*j within the chunk region -> contiguous, conflict-free.
            {
                int ii = b0 + sub;
                const int ic = ii < dcap ? ii : dcap - 1;   // clamp: benign dup
                const unsigned eid = (unsigned)__shfl(ev, ic);
                float4 v = *(const float4*)(ea + (size_t)eid * 16 + q * 4);
                *(float4*)&sea[w][ic * 16 + q * 4] = v;
            }
            // ---- issue 16 xa gathers into registers (static indexing) ----
            float xv[16];
#pragma unroll
            for (int t = 0; t < 16; ++t) {
                int ii = b0 + t;
                const int ic = ii < dcap ? ii : dcap - 1;   // uniform select
                const unsigned ss =
                    (unsigned)__builtin_amdgcn_readlane(sv, ic);
                xv[t] = (float)xa[(size_t)ss * 64 + j];
            }
            // ---- consume 16 edges ----
#pragma unroll
            for (int t = 0; t < 16; ++t) {
                const int ii = b0 + t;
                if (ii < dcap) {                            // uniform branch
                    const float4* ep = (const float4*)&sea[w][ii * 16];
                    float acc = base + xv[t];
                    FMA16(acc, ep, w1c);
                    hacc += fmaxf(acc, 0.f);
                }
            }
        }
    }

    // ---- fused epilogue: out[n] = hacc @ W2 + dcap * b2 ----
    sea[w][j] = hacc;                  // broadcast via LDS (wave-internal)
    float msg = (float)dcap * b2j;
#pragma unroll
    for (int k4 = 0; k4 < 16; ++k4) {
        float4 hv = *(const float4*)&sea[w][k4 * 4];        // uniform broadcast
        msg += hv.x * W2[(k4 * 4 + 0) * 64 + j];
        msg += hv.y * W2[(k4 * 4 + 1) * 64 + j];
        msg += hv.z * W2[(k4 * 4 + 2) * 64 + j];
        msg += hv.w * W2[(k4 * 4 + 3) * 64 + j];
    }
    out[(size_t)n * 64 + j] = msg;
}

// ---------------------------------------------------------------------------
// overflow_kernel: correctness net (expected 0 edges). Runs AFTER nodefused.
// ---------------------------------------------------------------------------
__global__ __launch_bounds__(256) void overflow_kernel(
    const f16* __restrict__ xa, const float* __restrict__ xb,
    const int* __restrict__ ei, const float* __restrict__ ea,
    const float* __restrict__ W1, const float* __restrict__ b1,
    const float* __restrict__ W2, const float* __restrict__ b2,
    const unsigned* __restrict__ ocnt, const unsigned* __restrict__ oflow,
    float* __restrict__ out)
{
    const unsigned oc = *ocnt;
    if (oc == 0) return;
    const int w = threadIdx.x >> 6;
    const int j = threadIdx.x & 63;
    unsigned idx = blockIdx.x * 4 + w;
    const unsigned stride = gridDim.x * 4;
    for (; idx < oc; idx += stride) {
        const int e = (int)oflow[idx];
        const int s = ei[e];
        const int dd = ei[N_EDGES + e];
        float acc = (float)xa[(size_t)s * 64 + j] +
                    xb[(size_t)dd * 64 + j] + b1[j];
        for (int k = 0; k < 16; ++k)
            acc += ea[(size_t)e * 16 + k] * W1[(128 + k) * 64 + j];
        const float h = fmaxf(acc, 0.f);
        float msg = b2[j];
        for (int k = 0; k < 64; ++k) msg += __shfl(h, k) * W2[k * 64 + j];
        unsafeAtomicAdd(&out[(size_t)dd * 64 + j], msg);
    }
}

// ---------------------------------------------------------------------------
// OLD PATH kernels (ws too small for bucketed pipeline) — fp32 throughout
// ---------------------------------------------------------------------------
__global__ __launch_bounds__(256) void pre_kernel(
    const float* __restrict__ x, const float* __restrict__ W1,
    float* __restrict__ xa, float* __restrict__ xb)
{
    const int w = threadIdx.x >> 6;
    const int j = threadIdx.x & 63;
    const int gw = blockIdx.x * 4 + w;
    const int p = gw & 1;
    const int pair = gw >> 1;
    const int npair = (gridDim.x * 4) >> 1;

    float wc[64];
#pragma unroll
    for (int k = 0; k < 64; ++k) wc[k] = W1[(p * 64 + k) * 64 + j];
    float* __restrict__ outp = p ? xb : xa;
    for (int i = pair; i < N_NODES; i += npair) {
        const float4* xr = (const float4*)&x[(size_t)i * 64];
        float acc = 0.f;
#pragma unroll
        for (int k4 = 0; k4 < 16; ++k4) {
            float4 xv = xr[k4];
            acc += xv.x * wc[k4 * 4 + 0];
            acc += xv.y * wc[k4 * 4 + 1];
            acc += xv.z * wc[k4 * 4 + 2];
            acc += xv.w * wc[k4 * 4 + 3];
        }
        outp[(size_t)i * 64 + j] = acc;
    }
}

__global__ __launch_bounds__(256) void edge_kernel(
    const float* __restrict__ xa, const float* __restrict__ xb,
    const int* __restrict__ ei,
    const float* __restrict__ edge_attr,
    const float* __restrict__ W1, const float* __restrict__ b1,
    const float* __restrict__ W2, const float* __restrict__ b2,
    float* __restrict__ out)
{
    __shared__ __align__(16) float eas[4][256];
    __shared__ __align__(16) float hs[4][16][64];

    const int w = threadIdx.x >> 6;
    const int j = threadIdx.x & 63;
    const int wt = blockIdx.x * 4 + w;
    const long eb = (long)wt * 16;

    float w1c[16];
    float w2c[64];
#pragma unroll
    for (int k = 0; k < 16; ++k) w1c[k] = W1[(128 + k) * 64 + j];
#pragma unroll
    for (int k = 0; k < 64; ++k) w2c[k] = W2[k * 64 + j];
    const float b1j = b1[j];
    const float b2j = b2[j];

    int idxv = 0;
    if (j < 16)       idxv = ei[eb + j];
    else if (j < 32)  idxv = ei[(long)N_EDGES + eb + (j - 16)];

    {
        float4 ev = *(const float4*)&edge_attr[eb * 16 + j * 4];
        *(float4*)&eas[w][j * 4] = ev;
    }

#pragma unroll 4
    for (int e = 0; e < 16; ++e) {
        const int s  = __shfl(idxv, e);
        const int dd = __shfl(idxv, 16 + e);

        float acc = xa[(long)s * 64 + j] + xb[(long)dd * 64 + j] + b1j;
#pragma unroll
        for (int k4 = 0; k4 < 4; ++k4) {
            float4 ev = *(const float4*)&eas[w][e * 16 + k4 * 4];
            acc += ev.x * w1c[k4 * 4 + 0];
            acc += ev.y * w1c[k4 * 4 + 1];
            acc += ev.z * w1c[k4 * 4 + 2];
            acc += ev.w * w1c[k4 * 4 + 3];
        }
        const float h = fmaxf(acc, 0.f);
        hs[w][e][j] = h;

        float msg = b2j;
#pragma unroll
        for (int k4 = 0; k4 < 16; ++k4) {
            float4 hv = *(const float4*)&hs[w][e][k4 * 4];
            msg += hv.x * w2c[k4 * 4 + 0];
            msg += hv.y * w2c[k4 * 4 + 1];
            msg += hv.z * w2c[k4 * 4 + 2];
            msg += hv.w * w2c[k4 * 4 + 3];
        }
        unsafeAtomicAdd(&out[(long)dd * 64 + j], msg);
    }
}

__global__ __launch_bounds__(256) void fallback_kernel(
    const float* __restrict__ x, const int* __restrict__ ei,
    const float* __restrict__ edge_attr,
    const float* __restrict__ W1, const float* __restrict__ b1,
    const float* __restrict__ W2, const float* __restrict__ b2,
    float* __restrict__ out)
{
    const int w = threadIdx.x >> 6;
    const int j = threadIdx.x & 63;
    const long e = (long)blockIdx.x * 4 + w;
    if (e >= N_EDGES) return;
    const int s  = ei[e];
    const int dd = ei[(long)N_EDGES + e];

    float acc = b1[j];
    for (int k = 0; k < 64; ++k) acc += x[(long)s  * 64 + k] * W1[k * 64 + j];
    for (int k = 0; k < 64; ++k) acc += x[(long)dd * 64 + k] * W1[(64 + k) * 64 + j];
    for (int k = 0; k < 16; ++k) acc += edge_attr[e * 16 + k] * W1[(128 + k) * 64 + j];
    const float h = fmaxf(acc, 0.f);

    float msg = b2[j];
    for (int k = 0; k < 64; ++k) msg += __shfl(h, k) * W2[k * 64 + j];
    unsafeAtomicAdd(&out[(long)dd * 64 + j], msg);
}

extern "C" void kernel_launch(void* const* d_in, const int* in_sizes, int n_in,
                              void* d_out, int out_size, void* d_ws, size_t ws_size,
                              hipStream_t stream) {
    const float* x   = (const float*)d_in[0];
    const int*   ei  = (const int*)d_in[1];
    const float* ea  = (const float*)d_in[2];
    const float* W1  = (const float*)d_in[3];
    const float* b1  = (const float*)d_in[4];
    const float* W2  = (const float*)d_in[5];
    const float* b2  = (const float*)d_in[6];
    float* out = (float*)d_out;

    const size_t NF = (size_t)N_NODES * 64;
    const size_t need_main = NF * 2 + NF * 4               // xa (f16), xb (f32)
                           + (size_t)N_NODES * 4 + 256     // cnt, ocnt(+pad)
                           + (size_t)N_NODES * CAP * 4     // slot (edge id)
                           + (size_t)N_EDGES * 4;          // oflow
    const size_t need_old = 2 * NF * 4;

    if (ws_size >= need_main) {
        char* p = (char*)d_ws;
        f16*      xauf  = (f16*)p;      p += NF * 2;
        float*    xbuf  = (float*)p;    p += NF * 4;
        unsigned* cnt   = (unsigned*)p; p += (size_t)N_NODES * 4;
        unsigned* ocnt  = (unsigned*)p; p += 256;
        unsigned* slot  = (unsigned*)p; p += (size_t)N_NODES * CAP * 4;
        unsigned* oflow = (unsigned*)p;

        hipMemsetAsync(cnt, 0, (size_t)N_NODES * 4 + 256, stream);
        prebuild_kernel<<<PB_BLOCKS, 256, 0, stream>>>(
            x, W1, xauf, xbuf, ei, cnt, ocnt, slot, oflow);
        nodefused_kernel<<<N_NODES / 4, 256, 0, stream>>>(
            xauf, xbuf, ea, slot, ei, cnt, W1, b1, W2, b2, out);
        overflow_kernel<<<16, 256, 0, stream>>>(xauf, xbuf, ei, ea, W1, b1,
                                                W2, b2, ocnt, oflow, out);
    } else if (ws_size >= need_old) {
        hipMemsetAsync(out, 0, (size_t)N_NODES * 64 * sizeof(float), stream);
        float* xauf = (float*)d_ws;
        float* xbuf = xauf + NF;
        pre_kernel<<<512, 256, 0, stream>>>(x, W1, xauf, xbuf);
        edge_kernel<<<N_EDGES / 64, 256, 0, stream>>>(xauf, xbuf, ei, ea,
                                                      W1, b1, W2, b2, out);
    } else {
        hipMemsetAsync(out, 0, (size_t)N_NODES * 64 * sizeof(float), stream);
        fallback_kernel<<<N_EDGES / 4, 256, 0, stream>>>(x, ei, ea,
                                                         W1, b1, W2, b2, out);
    }
}

// Round 12
// 225.439 us; speedup vs baseline: 1.2394x; 1.0200x over previous
//
#include <hip/hip_runtime.h>

#define N_NODES 50000
#define N_EDGES 800000
#define CAP 48
#define PB_BLOCKS 2560
typedef _Float16 f16;
typedef _Float16 h2 __attribute__((ext_vector_type(2)));
typedef _Float16 h4 __attribute__((ext_vector_type(4)));
// IN_F = 64, OUT_F = 64, EDGE_F = 16, d_in1 = 144
// NOTE: harness passes ALL integer inputs as int32 — edge_index is int32[2*E],
// src = ei[e], dst = ei[E+e].
// NOTE (round 3): hipLaunchCooperativeKernel broke the harness. NEVER coop.
// NOTE (round 6): few hot global atomic counters = serialization disaster.
// NOTE (rounds 5-8): prebuild's ~110us was vmcnt-serialized wave-uniform x
// loads; fixed via per-lane load -> LDS row -> broadcast ds_read (269->234).
// NOTE (round 9): __shfl honors EXEC — stage must be ALL-LANES-ACTIVE with
// clamped index. readlane ignores exec.
// NOTE (round 10): depth-32 stage = 16-way bank conflicts + VGPR overflow
// serialized gathers. 16-deep contiguous stage is the proven geometry.
// NOTE (round 11): FETCH 183->135MB changed duration 0% -> nodefused is
// ISSUE-bound (VALUBusy 70%), not BW-bound. Round 12: cut issue slots with
// v_dot2_f32_f16 on f16-staged ea (consume 23->13 slots/edge) and fold the
// overflow pass into nodefused (deg>CAP gate, never taken; removes a
// dispatch). No atomics on out remain.

#if defined(__has_builtin) && __has_builtin(__builtin_amdgcn_fdot2)
#define FDOT2(a, b, c) __builtin_amdgcn_fdot2((a), (b), (c), false)
#else
#define FDOT2(a, b, c) ((c) + (float)(a)[0] * (float)(b)[0] + (float)(a)[1] * (float)(b)[1])
#endif

// ---------------------------------------------------------------------------
// prebuild_kernel: EVERY block does
//   (1) build chunk: grid-stride over edges, bucket e by dst
//   (2) pre chunk: xa = x @ W1[0:64,:] (fp16), xb = x @ W1[64:128,:] (fp32)
//       per-lane coalesced x load -> per-wave LDS row -> broadcast
//       ds_read_b128; next row software-pipelined; 4 accumulator chains.
// cnt/ocnt must be zeroed before launch (memsetAsync).
// ---------------------------------------------------------------------------
__global__ __launch_bounds__(256) void prebuild_kernel(
    const float* __restrict__ x, const float* __restrict__ W1,
    f16* __restrict__ xa, float* __restrict__ xb,
    const int* __restrict__ ei, unsigned* __restrict__ cnt,
    unsigned* __restrict__ ocnt, unsigned* __restrict__ slot,
    unsigned* __restrict__ oflow)
{
    __shared__ __align__(16) float srow[4][64];   // per-wave x-row buffer

    const int tid = threadIdx.x;
    const int bid = blockIdx.x;

    // ---- build part: bucket edges by dst (store edge id only, 4 B) ----
    for (int e = bid * 256 + tid; e < N_EDGES; e += PB_BLOCKS * 256) {
        const int d = ei[N_EDGES + e];
        const unsigned pos = atomicAdd(&cnt[d], 1u);
        if (pos < CAP) {
            slot[(size_t)d * CAP + pos] = (unsigned)e;
        } else {
            const unsigned oi = atomicAdd(ocnt, 1u);
            oflow[oi] = (unsigned)e;
        }
    }

    // ---- pre part: wave per (node-subset, product) ----
    const int w = tid >> 6;
    const int j = tid & 63;
    const int gw = bid * 4 + w;
    const int p = gw & 1;              // 0 -> xa (f16), 1 -> xb (f32)
    const int pair = gw >> 1;
    const int npair = PB_BLOCKS * 2;   // 5120

    float wc[64];
#pragma unroll
    for (int k = 0; k < 64; ++k) wc[k] = W1[(p * 64 + k) * 64 + j];

    if (pair < N_NODES) {
        float xv = x[(size_t)pair * 64 + j];          // pipelined row element
        for (int i = pair; i < N_NODES; i += npair) {
            srow[w][j] = xv;                           // wave-internal LDS write
            const int inext = i + npair;
            float xnext = 0.f;
            if (inext < N_NODES) xnext = x[(size_t)inext * 64 + j];

            float a0 = 0.f, a1 = 0.f, a2 = 0.f, a3 = 0.f;
#pragma unroll
            for (int k4 = 0; k4 < 4; ++k4) {
                const float4 v0 = *(const float4*)&srow[w][k4 * 16 + 0];
                const float4 v1 = *(const float4*)&srow[w][k4 * 16 + 4];
                const float4 v2 = *(const float4*)&srow[w][k4 * 16 + 8];
                const float4 v3 = *(const float4*)&srow[w][k4 * 16 + 12];
                a0 += v0.x * wc[k4 * 16 + 0];  a0 += v0.y * wc[k4 * 16 + 1];
                a0 += v0.z * wc[k4 * 16 + 2];  a0 += v0.w * wc[k4 * 16 + 3];
                a1 += v1.x * wc[k4 * 16 + 4];  a1 += v1.y * wc[k4 * 16 + 5];
                a1 += v1.z * wc[k4 * 16 + 6];  a1 += v1.w * wc[k4 * 16 + 7];
                a2 += v2.x * wc[k4 * 16 + 8];  a2 += v2.y * wc[k4 * 16 + 9];
                a2 += v2.z * wc[k4 * 16 + 10]; a2 += v2.w * wc[k4 * 16 + 11];
                a3 += v3.x * wc[k4 * 16 + 12]; a3 += v3.y * wc[k4 * 16 + 13];
                a3 += v3.z * wc[k4 * 16 + 14]; a3 += v3.w * wc[k4 * 16 + 15];
            }
            const float val = (a0 + a1) + (a2 + a3);
            if (p) xb[(size_t)i * 64 + j] = val;          // wave-uniform branch
            else   xa[(size_t)i * 64 + j] = (f16)val;
            xv = xnext;
        }
    }
}

// ---------------------------------------------------------------------------
// nodefused_kernel: one wave per dst node.
//   hacc = sum_e relu(xa[src]+xb[n]+ea@W1c+b1)    (aggregation)
//   out[n] = hacc @ W2 + deg*b2                   (W2 hoisted out of seg-sum)
// 16-deep chunks (r8 geometry). ea staged in LDS as f16; consume uses
// v_dot2_f32_f16 (8 dot2 vs 16 fma per edge). Overflow edges (deg>CAP,
// ~never) handled inline by the owning wave -> no overflow dispatch, no
// atomics on out.
// ---------------------------------------------------------------------------
__global__ __launch_bounds__(256) void nodefused_kernel(
    const f16* __restrict__ xa, const float* __restrict__ xb,
    const float* __restrict__ ea, const unsigned* __restrict__ slot,
    const int* __restrict__ ei, const unsigned* __restrict__ cnt,
    const float* __restrict__ W1, const float* __restrict__ b1,
    const float* __restrict__ W2, const float* __restrict__ b2,
    const unsigned* __restrict__ ocnt, const unsigned* __restrict__ oflow,
    float* __restrict__ out)
{
    __shared__ __align__(16) f16   sea[4][CAP * 16];   // 6 KB: f16 ea tiles
    __shared__ __align__(16) float sh[4][64];          // 1 KB: hacc broadcast

    const int w = threadIdx.x >> 6;
    const int j = threadIdx.x & 63;
    const int n = blockIdx.x * 4 + w;

    // W1c column j as 8 f16 pairs (for dot2)
    h2 w1h[8];
#pragma unroll
    for (int r = 0; r < 8; ++r) {
        w1h[r][0] = (f16)W1[(128 + 2 * r) * 64 + j];
        w1h[r][1] = (f16)W1[(128 + 2 * r + 1) * 64 + j];
    }
    const float b1j = b1[j];
    const float b2j = b2[j];

    const int deg = (int)cnt[n];            // TRUE degree (may exceed CAP)
    const int dcap = deg < CAP ? deg : CAP;

    int ev = 0, sv = 0;
    if (j < dcap) {
        ev = (int)slot[(size_t)n * CAP + j];
        sv = ei[ev];
    }

    const float base = xb[(size_t)n * 64 + j] + b1j;

    float hacc = 0.f;
    if (dcap > 0) {
        const int sub = j >> 2;        // which edge of the chunk this lane stages
        const int q   = j & 3;         // which 4-float quarter of that edge

        for (int b0 = 0; b0 < dcap; b0 += 16) {
            // ---- stage ea rows (f32 global -> f16 LDS), 1 b64 write/lane ----
            // ALL lanes active, clamped index (r9 lesson); lane j writes LDS
            // byte 8*j within the chunk region -> contiguous, 2 lanes/bank.
            {
                int ii = b0 + sub;
                const int ic = ii < dcap ? ii : dcap - 1;   // clamp: benign dup
                const unsigned eid = (unsigned)__shfl(ev, ic);
                float4 v = *(const float4*)(ea + (size_t)eid * 16 + q * 4);
                h4 pv = {(f16)v.x, (f16)v.y, (f16)v.z, (f16)v.w};
                *(h4*)&sea[w][ic * 16 + q * 4] = pv;
            }
            // ---- issue 16 xa gathers into registers (static indexing) ----
            float xv[16];
#pragma unroll
            for (int t = 0; t < 16; ++t) {
                int ii = b0 + t;
                const int ic = ii < dcap ? ii : dcap - 1;   // uniform select
                const unsigned ss =
                    (unsigned)__builtin_amdgcn_readlane(sv, ic);
                xv[t] = (float)xa[(size_t)ss * 64 + j];
            }
            // ---- consume 16 edges: 2 ds_read_b128 + 8 dot2 each ----
#pragma unroll
            for (int t = 0; t < 16; ++t) {
                const int ii = b0 + t;
                if (ii < dcap) {                            // uniform branch
                    uint4 r0 = *(const uint4*)&sea[w][ii * 16];
                    uint4 r1 = *(const uint4*)&sea[w][ii * 16 + 8];
                    float acc = base + xv[t];
                    acc = FDOT2(__builtin_bit_cast(h2, r0.x), w1h[0], acc);
                    acc = FDOT2(__builtin_bit_cast(h2, r0.y), w1h[1], acc);
                    acc = FDOT2(__builtin_bit_cast(h2, r0.z), w1h[2], acc);
                    acc = FDOT2(__builtin_bit_cast(h2, r0.w), w1h[3], acc);
                    acc = FDOT2(__builtin_bit_cast(h2, r1.x), w1h[4], acc);
                    acc = FDOT2(__builtin_bit_cast(h2, r1.y), w1h[5], acc);
                    acc = FDOT2(__builtin_bit_cast(h2, r1.z), w1h[6], acc);
                    acc = FDOT2(__builtin_bit_cast(h2, r1.w), w1h[7], acc);
                    hacc += fmaxf(acc, 0.f);
                }
            }
        }
    }

    // ---- overflow fold (wave-uniform gate; expected never taken) ----
    if (deg > CAP) {
        const unsigned oc = *ocnt;
        for (unsigned t2 = 0; t2 < oc; ++t2) {
            const int e = (int)oflow[t2];
            if (ei[N_EDGES + e] == n) {
                const int s = ei[e];
                float acc = base + (float)xa[(size_t)s * 64 + j];
                for (int k = 0; k < 16; ++k)
                    acc += ea[(size_t)e * 16 + k] * W1[(128 + k) * 64 + j];
                hacc += fmaxf(acc, 0.f);
            }
        }
    }

    // ---- fused epilogue: out[n] = hacc @ W2 + deg * b2 ----
    sh[w][j] = hacc;                   // broadcast via LDS (wave-internal, f32)
    float msg = (float)deg * b2j;
#pragma unroll
    for (int k4 = 0; k4 < 16; ++k4) {
        float4 hv = *(const float4*)&sh[w][k4 * 4];         // uniform broadcast
        msg += hv.x * W2[(k4 * 4 + 0) * 64 + j];
        msg += hv.y * W2[(k4 * 4 + 1) * 64 + j];
        msg += hv.z * W2[(k4 * 4 + 2) * 64 + j];
        msg += hv.w * W2[(k4 * 4 + 3) * 64 + j];
    }
    out[(size_t)n * 64 + j] = msg;
}

// ---------------------------------------------------------------------------
// OLD PATH kernels (ws too small for bucketed pipeline) — fp32 throughout
// ---------------------------------------------------------------------------
__global__ __launch_bounds__(256) void pre_kernel(
    const float* __restrict__ x, const float* __restrict__ W1,
    float* __restrict__ xa, float* __restrict__ xb)
{
    const int w = threadIdx.x >> 6;
    const int j = threadIdx.x & 63;
    const int gw = blockIdx.x * 4 + w;
    const int p = gw & 1;
    const int pair = gw >> 1;
    const int npair = (gridDim.x * 4) >> 1;

    float wc[64];
#pragma unroll
    for (int k = 0; k < 64; ++k) wc[k] = W1[(p * 64 + k) * 64 + j];
    float* __restrict__ outp = p ? xb : xa;
    for (int i = pair; i < N_NODES; i += npair) {
        const float4* xr = (const float4*)&x[(size_t)i * 64];
        float acc = 0.f;
#pragma unroll
        for (int k4 = 0; k4 < 16; ++k4) {
            float4 xv = xr[k4];
            acc += xv.x * wc[k4 * 4 + 0];
            acc += xv.y * wc[k4 * 4 + 1];
            acc += xv.z * wc[k4 * 4 + 2];
            acc += xv.w * wc[k4 * 4 + 3];
        }
        outp[(size_t)i * 64 + j] = acc;
    }
}

__global__ __launch_bounds__(256) void edge_kernel(
    const float* __restrict__ xa, const float* __restrict__ xb,
    const int* __restrict__ ei,
    const float* __restrict__ edge_attr,
    const float* __restrict__ W1, const float* __restrict__ b1,
    const float* __restrict__ W2, const float* __restrict__ b2,
    float* __restrict__ out)
{
    __shared__ __align__(16) float eas[4][256];
    __shared__ __align__(16) float hs[4][16][64];

    const int w = threadIdx.x >> 6;
    const int j = threadIdx.x & 63;
    const int wt = blockIdx.x * 4 + w;
    const long eb = (long)wt * 16;

    float w1c[16];
    float w2c[64];
#pragma unroll
    for (int k = 0; k < 16; ++k) w1c[k] = W1[(128 + k) * 64 + j];
#pragma unroll
    for (int k = 0; k < 64; ++k) w2c[k] = W2[k * 64 + j];
    const float b1j = b1[j];
    const float b2j = b2[j];

    int idxv = 0;
    if (j < 16)       idxv = ei[eb + j];
    else if (j < 32)  idxv = ei[(long)N_EDGES + eb + (j - 16)];

    {
        float4 ev = *(const float4*)&edge_attr[eb * 16 + j * 4];
        *(float4*)&eas[w][j * 4] = ev;
    }

#pragma unroll 4
    for (int e = 0; e < 16; ++e) {
        const int s  = __shfl(idxv, e);
        const int dd = __shfl(idxv, 16 + e);

        float acc = xa[(long)s * 64 + j] + xb[(long)dd * 64 + j] + b1j;
#pragma unroll
        for (int k4 = 0; k4 < 4; ++k4) {
            float4 ev = *(const float4*)&eas[w][e * 16 + k4 * 4];
            acc += ev.x * w1c[k4 * 4 + 0];
            acc += ev.y * w1c[k4 * 4 + 1];
            acc += ev.z * w1c[k4 * 4 + 2];
            acc += ev.w * w1c[k4 * 4 + 3];
        }
        const float h = fmaxf(acc, 0.f);
        hs[w][e][j] = h;

        float msg = b2j;
#pragma unroll
        for (int k4 = 0; k4 < 16; ++k4) {
            float4 hv = *(const float4*)&hs[w][e][k4 * 4];
            msg += hv.x * w2c[k4 * 4 + 0];
            msg += hv.y * w2c[k4 * 4 + 1];
            msg += hv.z * w2c[k4 * 4 + 2];
            msg += hv.w * w2c[k4 * 4 + 3];
        }
        unsafeAtomicAdd(&out[(long)dd * 64 + j], msg);
    }
}

__global__ __launch_bounds__(256) void fallback_kernel(
    const float* __restrict__ x, const int* __restrict__ ei,
    const float* __restrict__ edge_attr,
    const float* __restrict__ W1, const float* __restrict__ b1,
    const float* __restrict__ W2, const float* __restrict__ b2,
    float* __restrict__ out)
{
    const int w = threadIdx.x >> 6;
    const int j = threadIdx.x & 63;
    const long e = (long)blockIdx.x * 4 + w;
    if (e >= N_EDGES) return;
    const int s  = ei[e];
    const int dd = ei[(long)N_EDGES + e];

    float acc = b1[j];
    for (int k = 0; k < 64; ++k) acc += x[(long)s  * 64 + k] * W1[k * 64 + j];
    for (int k = 0; k < 64; ++k) acc += x[(long)dd * 64 + k] * W1[(64 + k) * 64 + j];
    for (int k = 0; k < 16; ++k) acc += edge_attr[e * 16 + k] * W1[(128 + k) * 64 + j];
    const float h = fmaxf(acc, 0.f);

    float msg = b2[j];
    for (int k = 0; k < 64; ++k) msg += __shfl(h, k) * W2[k * 64 + j];
    unsafeAtomicAdd(&out[(long)dd * 64 + j], msg);
}

extern "C" void kernel_launch(void* const* d_in, const int* in_sizes, int n_in,
                              void* d_out, int out_size, void* d_ws, size_t ws_size,
                              hipStream_t stream) {
    const float* x   = (const float*)d_in[0];
    const int*   ei  = (const int*)d_in[1];
    const float* ea  = (const float*)d_in[2];
    const float* W1  = (const float*)d_in[3];
    const float* b1  = (const float*)d_in[4];
    const float* W2  = (const float*)d_in[5];
    const float* b2  = (const float*)d_in[6];
    float* out = (float*)d_out;

    const size_t NF = (size_t)N_NODES * 64;
    const size_t need_main = NF * 2 + NF * 4               // xa (f16), xb (f32)
                           + (size_t)N_NODES * 4 + 256     // cnt, ocnt(+pad)
                           + (size_t)N_NODES * CAP * 4     // slot (edge id)
                           + (size_t)N_EDGES * 4;          // oflow
    const size_t need_old = 2 * NF * 4;

    if (ws_size >= need_main) {
        char* p = (char*)d_ws;
        f16*      xauf  = (f16*)p;      p += NF * 2;
        float*    xbuf  = (float*)p;    p += NF * 4;
        unsigned* cnt   = (unsigned*)p; p += (size_t)N_NODES * 4;
        unsigned* ocnt  = (unsigned*)p; p += 256;
        unsigned* slot  = (unsigned*)p; p += (size_t)N_NODES * CAP * 4;
        unsigned* oflow = (unsigned*)p;

        hipMemsetAsync(cnt, 0, (size_t)N_NODES * 4 + 256, stream);
        prebuild_kernel<<<PB_BLOCKS, 256, 0, stream>>>(
            x, W1, xauf, xbuf, ei, cnt, ocnt, slot, oflow);
        nodefused_kernel<<<N_NODES / 4, 256, 0, stream>>>(
            xauf, xbuf, ea, slot, ei, cnt, W1, b1, W2, b2, ocnt, oflow, out);
    } else if (ws_size >= need_old) {
        hipMemsetAsync(out, 0, (size_t)N_NODES * 64 * sizeof(float), stream);
        float* xauf = (float*)d_ws;
        float* xbuf = xauf + NF;
        pre_kernel<<<512, 256, 0, stream>>>(x, W1, xauf, xbuf);
        edge_kernel<<<N_EDGES / 64, 256, 0, stream>>>(xauf, xbuf, ei, ea,
                                                      W1, b1, W2, b2, out);
    } else {
        hipMemsetAsync(out, 0, (size_t)N_NODES * 64 * sizeof(float), stream);
        fallback_kernel<<<N_EDGES / 4, 256, 0, stream>>>(x, ei, ea,
                                                         W1, b1, W2, b2, out);
    }
}

// Round 13
// 223.113 us; speedup vs baseline: 1.2523x; 1.0104x over previous
//
#include <hip/hip_runtime.h>

#define N_NODES 50000
#define N_EDGES 800000
#define CAP 48
#define PB_BLOCKS 2560
typedef _Float16 f16;
typedef _Float16 h2 __attribute__((ext_vector_type(2)));
typedef _Float16 h4 __attribute__((ext_vector_type(4)));
// IN_F = 64, OUT_F = 64, EDGE_F = 16, d_in1 = 144
// NOTE: harness passes ALL integer inputs as int32 — edge_index is int32[2*E],
// src = ei[e], dst = ei[E+e].
// NOTE (round 3): hipLaunchCooperativeKernel broke the harness. NEVER coop.
// NOTE (round 6): few hot global atomic counters = serialization disaster.
// NOTE (round 9): __shfl honors EXEC — stage must be ALL-LANES-ACTIVE with
// clamped index. readlane ignores exec.
// NOTE (round 10): depth-32 stage = bank conflicts + VGPR spill-serialized
// gathers. 16-deep contiguous stage is the proven geometry.
// NOTE (round 11): FETCH 183->135MB changed duration 0% -> not BW-bound.
// NOTE (round 12): dot2 cut VALUBusy 70->51% but dur only 83->76 ->
// nodefused is DEPENDENT-LATENCY-bound: slot -> ei[ev] -> xa is a 3-hop
// scattered chain per wave. Round 13: uint2 slot stores (src,e) directly
// (removes the ei hop; scattered-write cost is line-move-dominated, proven
// payload-insensitive in r5/r7) + split hacc accumulator chain.

#if defined(__has_builtin) && __has_builtin(__builtin_amdgcn_fdot2)
#define FDOT2(a, b, c) __builtin_amdgcn_fdot2((a), (b), (c), false)
#else
#define FDOT2(a, b, c) ((c) + (float)(a)[0] * (float)(b)[0] + (float)(a)[1] * (float)(b)[1])
#endif

// ---------------------------------------------------------------------------
// prebuild_kernel: EVERY block does
//   (1) build chunk: grid-stride over edges, bucket e by dst: slot=(src,e)
//   (2) pre chunk: xa = x @ W1[0:64,:] (fp16), xb = x @ W1[64:128,:] (fp32)
//       per-lane coalesced x load -> per-wave LDS row -> broadcast
//       ds_read_b128; next row software-pipelined; 4 accumulator chains.
// cnt/ocnt must be zeroed before launch (memsetAsync).
// ---------------------------------------------------------------------------
__global__ __launch_bounds__(256) void prebuild_kernel(
    const float* __restrict__ x, const float* __restrict__ W1,
    f16* __restrict__ xa, float* __restrict__ xb,
    const int* __restrict__ ei, unsigned* __restrict__ cnt,
    unsigned* __restrict__ ocnt, uint2* __restrict__ slot,
    unsigned* __restrict__ oflow)
{
    __shared__ __align__(16) float srow[4][64];   // per-wave x-row buffer

    const int tid = threadIdx.x;
    const int bid = blockIdx.x;

    // ---- build part: bucket edges by dst; slot holds (src, edge) 8 B ----
    for (int e = bid * 256 + tid; e < N_EDGES; e += PB_BLOCKS * 256) {
        const int s = ei[e];
        const int d = ei[N_EDGES + e];
        const unsigned pos = atomicAdd(&cnt[d], 1u);
        if (pos < CAP) {
            slot[(size_t)d * CAP + pos] = make_uint2((unsigned)s, (unsigned)e);
        } else {
            const unsigned oi = atomicAdd(ocnt, 1u);
            oflow[oi] = (unsigned)e;
        }
    }

    // ---- pre part: wave per (node-subset, product) ----
    const int w = tid >> 6;
    const int j = tid & 63;
    const int gw = bid * 4 + w;
    const int p = gw & 1;              // 0 -> xa (f16), 1 -> xb (f32)
    const int pair = gw >> 1;
    const int npair = PB_BLOCKS * 2;   // 5120

    float wc[64];
#pragma unroll
    for (int k = 0; k < 64; ++k) wc[k] = W1[(p * 64 + k) * 64 + j];

    if (pair < N_NODES) {
        float xv = x[(size_t)pair * 64 + j];          // pipelined row element
        for (int i = pair; i < N_NODES; i += npair) {
            srow[w][j] = xv;                           // wave-internal LDS write
            const int inext = i + npair;
            float xnext = 0.f;
            if (inext < N_NODES) xnext = x[(size_t)inext * 64 + j];

            float a0 = 0.f, a1 = 0.f, a2 = 0.f, a3 = 0.f;
#pragma unroll
            for (int k4 = 0; k4 < 4; ++k4) {
                const float4 v0 = *(const float4*)&srow[w][k4 * 16 + 0];
                const float4 v1 = *(const float4*)&srow[w][k4 * 16 + 4];
                const float4 v2 = *(const float4*)&srow[w][k4 * 16 + 8];
                const float4 v3 = *(const float4*)&srow[w][k4 * 16 + 12];
                a0 += v0.x * wc[k4 * 16 + 0];  a0 += v0.y * wc[k4 * 16 + 1];
                a0 += v0.z * wc[k4 * 16 + 2];  a0 += v0.w * wc[k4 * 16 + 3];
                a1 += v1.x * wc[k4 * 16 + 4];  a1 += v1.y * wc[k4 * 16 + 5];
                a1 += v1.z * wc[k4 * 16 + 6];  a1 += v1.w * wc[k4 * 16 + 7];
                a2 += v2.x * wc[k4 * 16 + 8];  a2 += v2.y * wc[k4 * 16 + 9];
                a2 += v2.z * wc[k4 * 16 + 10]; a2 += v2.w * wc[k4 * 16 + 11];
                a3 += v3.x * wc[k4 * 16 + 12]; a3 += v3.y * wc[k4 * 16 + 13];
                a3 += v3.z * wc[k4 * 16 + 14]; a3 += v3.w * wc[k4 * 16 + 15];
            }
            const float val = (a0 + a1) + (a2 + a3);
            if (p) xb[(size_t)i * 64 + j] = val;          // wave-uniform branch
            else   xa[(size_t)i * 64 + j] = (f16)val;
            xv = xnext;
        }
    }
}

// ---------------------------------------------------------------------------
// nodefused_kernel: one wave per dst node.
//   hacc = sum_e relu(xa[src]+xb[n]+ea@W1c+b1)    (aggregation)
//   out[n] = hacc @ W2 + deg*b2                   (W2 hoisted out of seg-sum)
// uint2 slot gives (src,e) in ONE scattered load -> 2-hop chain (slot->xa).
// 16-deep chunks; ea staged f16; dot2 consume; 2 hacc chains; overflow
// folded inline (deg>CAP, ~never). No atomics on out.
// ---------------------------------------------------------------------------
__global__ __launch_bounds__(256) void nodefused_kernel(
    const f16* __restrict__ xa, const float* __restrict__ xb,
    const float* __restrict__ ea, const uint2* __restrict__ slot,
    const int* __restrict__ ei, const unsigned* __restrict__ cnt,
    const float* __restrict__ W1, const float* __restrict__ b1,
    const float* __restrict__ W2, const float* __restrict__ b2,
    const unsigned* __restrict__ ocnt, const unsigned* __restrict__ oflow,
    float* __restrict__ out)
{
    __shared__ __align__(16) f16   sea[4][CAP * 16];   // 6 KB: f16 ea tiles
    __shared__ __align__(16) float sh[4][64];          // 1 KB: hacc broadcast

    const int w = threadIdx.x >> 6;
    const int j = threadIdx.x & 63;
    const int n = blockIdx.x * 4 + w;

    // W1c column j as 8 f16 pairs (for dot2)
    h2 w1h[8];
#pragma unroll
    for (int r = 0; r < 8; ++r) {
        w1h[r][0] = (f16)W1[(128 + 2 * r) * 64 + j];
        w1h[r][1] = (f16)W1[(128 + 2 * r + 1) * 64 + j];
    }
    const float b1j = b1[j];
    const float b2j = b2[j];

    const int deg = (int)cnt[n];            // TRUE degree (may exceed CAP)
    const int dcap = deg < CAP ? deg : CAP;

    // ONE scattered load gives both src and edge id (no ei hop)
    uint2 my = make_uint2(0u, 0u);
    if (j < dcap) my = slot[(size_t)n * CAP + j];
    const int sv = (int)my.x;
    const int ev = (int)my.y;

    const float base = xb[(size_t)n * 64 + j] + b1j;

    float hacc = 0.f;
    if (dcap > 0) {
        const int sub = j >> 2;        // which edge of the chunk this lane stages
        const int q   = j & 3;         // which 4-float quarter of that edge
        float h0 = 0.f, h1 = 0.f;      // split accumulator chains

        for (int b0 = 0; b0 < dcap; b0 += 16) {
            // ---- stage ea rows (f32 global -> f16 LDS), 1 b64 write/lane ----
            // ALL lanes active, clamped index (r9 lesson); contiguous bytes.
            {
                int ii = b0 + sub;
                const int ic = ii < dcap ? ii : dcap - 1;   // clamp: benign dup
                const unsigned eid = (unsigned)__shfl(ev, ic);
                float4 v = *(const float4*)(ea + (size_t)eid * 16 + q * 4);
                h4 pv = {(f16)v.x, (f16)v.y, (f16)v.z, (f16)v.w};
                *(h4*)&sea[w][ic * 16 + q * 4] = pv;
            }
            // ---- issue 16 xa gathers into registers (static indexing) ----
            float xv[16];
#pragma unroll
            for (int t = 0; t < 16; ++t) {
                int ii = b0 + t;
                const int ic = ii < dcap ? ii : dcap - 1;   // uniform select
                const unsigned ss =
                    (unsigned)__builtin_amdgcn_readlane(sv, ic);
                xv[t] = (float)xa[(size_t)ss * 64 + j];
            }
            // ---- consume 16 edges: 2 ds_read_b128 + 8 dot2 each ----
#pragma unroll
            for (int t = 0; t < 16; ++t) {
                const int ii = b0 + t;
                if (ii < dcap) {                            // uniform branch
                    uint4 r0 = *(const uint4*)&sea[w][ii * 16];
                    uint4 r1 = *(const uint4*)&sea[w][ii * 16 + 8];
                    float acc = base + xv[t];
                    acc = FDOT2(__builtin_bit_cast(h2, r0.x), w1h[0], acc);
                    acc = FDOT2(__builtin_bit_cast(h2, r0.y), w1h[1], acc);
                    acc = FDOT2(__builtin_bit_cast(h2, r0.z), w1h[2], acc);
                    acc = FDOT2(__builtin_bit_cast(h2, r0.w), w1h[3], acc);
                    acc = FDOT2(__builtin_bit_cast(h2, r1.x), w1h[4], acc);
                    acc = FDOT2(__builtin_bit_cast(h2, r1.y), w1h[5], acc);
                    acc = FDOT2(__builtin_bit_cast(h2, r1.z), w1h[6], acc);
                    acc = FDOT2(__builtin_bit_cast(h2, r1.w), w1h[7], acc);
                    if (t & 1) h1 += fmaxf(acc, 0.f);
                    else       h0 += fmaxf(acc, 0.f);
                }
            }
        }
        hacc = h0 + h1;
    }

    // ---- overflow fold (wave-uniform gate; expected never taken) ----
    if (deg > CAP) {
        const unsigned oc = *ocnt;
        for (unsigned t2 = 0; t2 < oc; ++t2) {
            const int e = (int)oflow[t2];
            if (ei[N_EDGES + e] == n) {
                const int s = ei[e];
                float acc = base + (float)xa[(size_t)s * 64 + j];
                for (int k = 0; k < 16; ++k)
                    acc += ea[(size_t)e * 16 + k] * W1[(128 + k) * 64 + j];
                hacc += fmaxf(acc, 0.f);
            }
        }
    }

    // ---- fused epilogue: out[n] = hacc @ W2 + deg * b2 ----
    sh[w][j] = hacc;                   // broadcast via LDS (wave-internal, f32)
    float msg = (float)deg * b2j;
#pragma unroll
    for (int k4 = 0; k4 < 16; ++k4) {
        float4 hv = *(const float4*)&sh[w][k4 * 4];         // uniform broadcast
        msg += hv.x * W2[(k4 * 4 + 0) * 64 + j];
        msg += hv.y * W2[(k4 * 4 + 1) * 64 + j];
        msg += hv.z * W2[(k4 * 4 + 2) * 64 + j];
        msg += hv.w * W2[(k4 * 4 + 3) * 64 + j];
    }
    out[(size_t)n * 64 + j] = msg;
}

// ---------------------------------------------------------------------------
// OLD PATH kernels (ws too small for bucketed pipeline) — fp32 throughout
// ---------------------------------------------------------------------------
__global__ __launch_bounds__(256) void pre_kernel(
    const float* __restrict__ x, const float* __restrict__ W1,
    float* __restrict__ xa, float* __restrict__ xb)
{
    const int w = threadIdx.x >> 6;
    const int j = threadIdx.x & 63;
    const int gw = blockIdx.x * 4 + w;
    const int p = gw & 1;
    const int pair = gw >> 1;
    const int npair = (gridDim.x * 4) >> 1;

    float wc[64];
#pragma unroll
    for (int k = 0; k < 64; ++k) wc[k] = W1[(p * 64 + k) * 64 + j];
    float* __restrict__ outp = p ? xb : xa;
    for (int i = pair; i < N_NODES; i += npair) {
        const float4* xr = (const float4*)&x[(size_t)i * 64];
        float acc = 0.f;
#pragma unroll
        for (int k4 = 0; k4 < 16; ++k4) {
            float4 xv = xr[k4];
            acc += xv.x * wc[k4 * 4 + 0];
            acc += xv.y * wc[k4 * 4 + 1];
            acc += xv.z * wc[k4 * 4 + 2];
            acc += xv.w * wc[k4 * 4 + 3];
        }
        outp[(size_t)i * 64 + j] = acc;
    }
}

__global__ __launch_bounds__(256) void edge_kernel(
    const float* __restrict__ xa, const float* __restrict__ xb,
    const int* __restrict__ ei,
    const float* __restrict__ edge_attr,
    const float* __restrict__ W1, const float* __restrict__ b1,
    const float* __restrict__ W2, const float* __restrict__ b2,
    float* __restrict__ out)
{
    __shared__ __align__(16) float eas[4][256];
    __shared__ __align__(16) float hs[4][16][64];

    const int w = threadIdx.x >> 6;
    const int j = threadIdx.x & 63;
    const int wt = blockIdx.x * 4 + w;
    const long eb = (long)wt * 16;

    float w1c[16];
    float w2c[64];
#pragma unroll
    for (int k = 0; k < 16; ++k) w1c[k] = W1[(128 + k) * 64 + j];
#pragma unroll
    for (int k = 0; k < 64; ++k) w2c[k] = W2[k * 64 + j];
    const float b1j = b1[j];
    const float b2j = b2[j];

    int idxv = 0;
    if (j < 16)       idxv = ei[eb + j];
    else if (j < 32)  idxv = ei[(long)N_EDGES + eb + (j - 16)];

    {
        float4 ev = *(const float4*)&edge_attr[eb * 16 + j * 4];
        *(float4*)&eas[w][j * 4] = ev;
    }

#pragma unroll 4
    for (int e = 0; e < 16; ++e) {
        const int s  = __shfl(idxv, e);
        const int dd = __shfl(idxv, 16 + e);

        float acc = xa[(long)s * 64 + j] + xb[(long)dd * 64 + j] + b1j;
#pragma unroll
        for (int k4 = 0; k4 < 4; ++k4) {
            float4 ev = *(const float4*)&eas[w][e * 16 + k4 * 4];
            acc += ev.x * w1c[k4 * 4 + 0];
            acc += ev.y * w1c[k4 * 4 + 1];
            acc += ev.z * w1c[k4 * 4 + 2];
            acc += ev.w * w1c[k4 * 4 + 3];
        }
        const float h = fmaxf(acc, 0.f);
        hs[w][e][j] = h;

        float msg = b2j;
#pragma unroll
        for (int k4 = 0; k4 < 16; ++k4) {
            float4 hv = *(const float4*)&hs[w][e][k4 * 4];
            msg += hv.x * w2c[k4 * 4 + 0];
            msg += hv.y * w2c[k4 * 4 + 1];
            msg += hv.z * w2c[k4 * 4 + 2];
            msg += hv.w * w2c[k4 * 4 + 3];
        }
        unsafeAtomicAdd(&out[(long)dd * 64 + j], msg);
    }
}

__global__ __launch_bounds__(256) void fallback_kernel(
    const float* __restrict__ x, const int* __restrict__ ei,
    const float* __restrict__ edge_attr,
    const float* __restrict__ W1, const float* __restrict__ b1,
    const float* __restrict__ W2, const float* __restrict__ b2,
    float* __restrict__ out)
{
    const int w = threadIdx.x >> 6;
    const int j = threadIdx.x & 63;
    const long e = (long)blockIdx.x * 4 + w;
    if (e >= N_EDGES) return;
    const int s  = ei[e];
    const int dd = ei[(long)N_EDGES + e];

    float acc = b1[j];
    for (int k = 0; k < 64; ++k) acc += x[(long)s  * 64 + k] * W1[k * 64 + j];
    for (int k = 0; k < 64; ++k) acc += x[(long)dd * 64 + k] * W1[(64 + k) * 64 + j];
    for (int k = 0; k < 16; ++k) acc += edge_attr[e * 16 + k] * W1[(128 + k) * 64 + j];
    const float h = fmaxf(acc, 0.f);

    float msg = b2[j];
    for (int k = 0; k < 64; ++k) msg += __shfl(h, k) * W2[k * 64 + j];
    unsafeAtomicAdd(&out[(long)dd * 64 + j], msg);
}

extern "C" void kernel_launch(void* const* d_in, const int* in_sizes, int n_in,
                              void* d_out, int out_size, void* d_ws, size_t ws_size,
                              hipStream_t stream) {
    const float* x   = (const float*)d_in[0];
    const int*   ei  = (const int*)d_in[1];
    const float* ea  = (const float*)d_in[2];
    const float* W1  = (const float*)d_in[3];
    const float* b1  = (const float*)d_in[4];
    const float* W2  = (const float*)d_in[5];
    const float* b2  = (const float*)d_in[6];
    float* out = (float*)d_out;

    const size_t NF = (size_t)N_NODES * 64;
    const size_t need_main = NF * 2 + NF * 4               // xa (f16), xb (f32)
                           + (size_t)N_NODES * 4 + 256     // cnt, ocnt(+pad)
                           + (size_t)N_NODES * CAP * 8     // slot (uint2)
                           + (size_t)N_EDGES * 4;          // oflow
    const size_t need_old = 2 * NF * 4;

    if (ws_size >= need_main) {
        char* p = (char*)d_ws;
        f16*      xauf  = (f16*)p;      p += NF * 2;
        float*    xbuf  = (float*)p;    p += NF * 4;
        unsigned* cnt   = (unsigned*)p; p += (size_t)N_NODES * 4;
        unsigned* ocnt  = (unsigned*)p; p += 256;
        uint2*    slot  = (uint2*)p;    p += (size_t)N_NODES * CAP * 8;
        unsigned* oflow = (unsigned*)p;

        hipMemsetAsync(cnt, 0, (size_t)N_NODES * 4 + 256, stream);
        prebuild_kernel<<<PB_BLOCKS, 256, 0, stream>>>(
            x, W1, xauf, xbuf, ei, cnt, ocnt, slot, oflow);
        nodefused_kernel<<<N_NODES / 4, 256, 0, stream>>>(
            xauf, xbuf, ea, slot, ei, cnt, W1, b1, W2, b2, ocnt, oflow, out);
    } else if (ws_size >= need_old) {
        hipMemsetAsync(out, 0, (size_t)N_NODES * 64 * sizeof(float), stream);
        float* xauf = (float*)d_ws;
        float* xbuf = xauf + NF;
        pre_kernel<<<512, 256, 0, stream>>>(x, W1, xauf, xbuf);
        edge_kernel<<<N_EDGES / 64, 256, 0, stream>>>(xauf, xbuf, ei, ea,
                                                      W1, b1, W2, b2, out);
    } else {
        hipMemsetAsync(out, 0, (size_t)N_NODES * 64 * sizeof(float), stream);
        fallback_kernel<<<N_EDGES / 4, 256, 0, stream>>>(x, ei, ea,
                                                         W1, b1, W2, b2, out);
    }
}